// Round 1
// baseline (14.594 us; speedup 1.0000x reference)
//
#include <hip/hip_runtime.h>

// Problem shape (hardcoded from reference setup_inputs):
//   x: (8, 2, 512, 512) f32 ; out: (8, 2, 512, 512) f32
//   W1,B1,W2,B2,W3: (4,16) ; B3: (4,)
// Algebra: grads[k](s) = A[k]*s^2 + Bc[k]*s + Cc[k]
//   A[k]  = sum_c W3[k,c]*W1[k,c]*W2[k,c]
//   Bc[k] = sum_c W3[k,c]*(W1[k,c]*B2[k,c] + B1[k,c]*W2[k,c])
//   Cc[k] = sum_c W3[k,c]*B1[k,c]*B2[k,c] + B3[k]
// k=0,1 evaluated at s=u ; k=2,3 at s=v.
// out_u = u*g0(u) + v*g1(u) ; out_v = u*g2(v) + v*g3(v)

#define BATCH 8
#define HW    (512 * 512)
#define HW4   (HW / 4)          // 65536 float4 per plane
#define TOTAL4 (BATCH * HW4)    // 524288

__global__ void percnn_coeff_kernel(const float* __restrict__ W1,
                                    const float* __restrict__ B1,
                                    const float* __restrict__ W2,
                                    const float* __restrict__ B2,
                                    const float* __restrict__ W3,
                                    const float* __restrict__ B3,
                                    float* __restrict__ coef) {
    int k = threadIdx.x;
    if (k < 4) {
        float A = 0.f, Bc = 0.f, Cc = 0.f;
        for (int c = 0; c < 16; ++c) {
            float w1 = W1[k * 16 + c], b1 = B1[k * 16 + c];
            float w2 = W2[k * 16 + c], b2 = B2[k * 16 + c];
            float w3 = W3[k * 16 + c];
            A  += w3 * w1 * w2;
            Bc += w3 * (w1 * b2 + b1 * w2);
            Cc += w3 * (b1 * b2);
        }
        Cc += B3[k];
        coef[0 + k] = A;
        coef[4 + k] = Bc;
        coef[8 + k] = Cc;
    }
}

__global__ __launch_bounds__(256) void percnn_main_kernel(
        const float4* __restrict__ x,
        float4* __restrict__ out,
        const float* __restrict__ coef) {
    // Uniform coefficient loads (scalar path).
    const float A0 = coef[0], A1 = coef[1], A2 = coef[2], A3 = coef[3];
    const float b0 = coef[4], b1 = coef[5], b2 = coef[6], b3 = coef[7];
    const float c0 = coef[8], c1 = coef[9], c2 = coef[10], c3 = coef[11];

    const int idx = blockIdx.x * blockDim.x + threadIdx.x;
    if (idx >= TOTAL4) return;
    const int b = idx >> 16;          // idx / HW4   (HW4 = 65536)
    const int i = idx & (HW4 - 1);    // idx % HW4

    const size_t uoff = (size_t)(b * 2 + 0) * HW4 + i;
    const size_t voff = (size_t)(b * 2 + 1) * HW4 + i;

    const float4 u4 = x[uoff];
    const float4 v4 = x[voff];

    float4 ou, ov;
    #pragma unroll
    for (int j = 0; j < 4; ++j) {
        const float u = (&u4.x)[j];
        const float v = (&v4.x)[j];
        // Horner: g = (A*s + b)*s + c
        const float g0 = fmaf(fmaf(A0, u, b0), u, c0);
        const float g1 = fmaf(fmaf(A1, u, b1), u, c1);
        const float g2 = fmaf(fmaf(A2, v, b2), v, c2);
        const float g3 = fmaf(fmaf(A3, v, b3), v, c3);
        (&ou.x)[j] = fmaf(u, g0, v * g1);
        (&ov.x)[j] = fmaf(u, g2, v * g3);
    }

    out[uoff] = ou;
    out[voff] = ov;
}

extern "C" void kernel_launch(void* const* d_in, const int* in_sizes, int n_in,
                              void* d_out, int out_size, void* d_ws, size_t ws_size,
                              hipStream_t stream) {
    const float* x  = (const float*)d_in[0];
    const float* W1 = (const float*)d_in[1];
    const float* B1 = (const float*)d_in[2];
    const float* W2 = (const float*)d_in[3];
    const float* B2 = (const float*)d_in[4];
    const float* W3 = (const float*)d_in[5];
    const float* B3 = (const float*)d_in[6];
    float* out  = (float*)d_out;
    float* coef = (float*)d_ws;   // 12 floats

    percnn_coeff_kernel<<<1, 64, 0, stream>>>(W1, B1, W2, B2, W3, B3, coef);

    const int threads = 256;
    const int blocks = (TOTAL4 + threads - 1) / threads;  // 2048
    percnn_main_kernel<<<blocks, threads, 0, stream>>>(
        (const float4*)x, (float4*)out, coef);
}

// Round 2
// 11.503 us; speedup vs baseline: 1.2687x; 1.2687x over previous
//
#include <hip/hip_runtime.h>

// x: (8, 2, 512, 512) f32 ; out: (8, 2, 512, 512) f32
// W1,B1,W2,B2,W3: (4,16) f32 ; B3: (4,) f32
//
// Algebra: grads[k](s) = A[k]*s^2 + B[k]*s + C[k]
//   A[k] = sum_c W3[k,c]*W1[k,c]*W2[k,c]
//   B[k] = sum_c W3[k,c]*(W1[k,c]*B2[k,c] + B1[k,c]*W2[k,c])
//   C[k] = sum_c W3[k,c]*B1[k,c]*B2[k,c] + B3[k]
// k=0,1 at s=u ; k=2,3 at s=v.
// out_u = u*g0(u) + v*g1(u) ; out_v = u*g2(v) + v*g3(v)
//
// Fused single kernel: each WAVE computes the 12 coefficients lane-parallel
// (lane = k*16+c indexes the (4,16) weight arrays directly -> coalesced 256B
// loads), reduces over c with a 4-step shfl_xor butterfly, broadcasts via
// shfl. ~250 cyc/wave, hidden under memory latency. Then 2 float4 pixel
// groups per thread, coalesced.

#define BATCH  8
#define HW     (512 * 512)
#define HW4    (HW / 4)            // 65536 float4 per plane
#define TOTAL4 (BATCH * HW4)       // 524288 float4 groups per field
#define PER_THREAD 2
#define THREADS 256
#define BLOCKS  (TOTAL4 / (THREADS * PER_THREAD))   // 1024

__global__ __launch_bounds__(THREADS) void percnn_fused_kernel(
        const float4* __restrict__ x,
        float4* __restrict__ out,
        const float* __restrict__ W1,
        const float* __restrict__ B1,
        const float* __restrict__ W2,
        const float* __restrict__ B2,
        const float* __restrict__ W3,
        const float* __restrict__ B3) {
    // ---- per-wave coefficient computation (lane = k*16 + c) ----
    const int lane = threadIdx.x & 63;
    const float w1 = W1[lane], bb1 = B1[lane];
    const float w2 = W2[lane], bb2 = B2[lane];
    const float w3 = W3[lane];

    float pA = w3 * w1 * w2;
    float pB = w3 * fmaf(w1, bb2, bb1 * w2);
    float pC = w3 * bb1 * bb2;

    // reduce over the 16 lanes of each k-group (masks 8,4,2,1 stay in-group)
    #pragma unroll
    for (int off = 8; off >= 1; off >>= 1) {
        pA += __shfl_xor(pA, off);
        pB += __shfl_xor(pB, off);
        pC += __shfl_xor(pC, off);
    }
    // every lane of group k now holds the full sum for k; broadcast all 4
    const float A0 = __shfl(pA, 0),  A1 = __shfl(pA, 16);
    const float A2 = __shfl(pA, 32), A3 = __shfl(pA, 48);
    const float c10 = __shfl(pB, 0),  c11 = __shfl(pB, 16);
    const float c12 = __shfl(pB, 32), c13 = __shfl(pB, 48);
    const float c00 = __shfl(pC, 0)  + B3[0];
    const float c01 = __shfl(pC, 16) + B3[1];
    const float c02 = __shfl(pC, 32) + B3[2];
    const float c03 = __shfl(pC, 48) + B3[3];

    // ---- main elementwise work: 2 float4 groups per thread ----
    const int tid = blockIdx.x * THREADS + threadIdx.x;
    #pragma unroll
    for (int r = 0; r < PER_THREAD; ++r) {
        const int idx = tid + r * (TOTAL4 / PER_THREAD);
        const int b = idx >> 16;           // / HW4
        const int i = idx & (HW4 - 1);     // % HW4

        const size_t uoff = (size_t)(b * 2 + 0) * HW4 + i;
        const size_t voff = (size_t)(b * 2 + 1) * HW4 + i;

        const float4 u4 = x[uoff];
        const float4 v4 = x[voff];

        float4 ou, ov;
        #pragma unroll
        for (int j = 0; j < 4; ++j) {
            const float u = (&u4.x)[j];
            const float v = (&v4.x)[j];
            const float g0 = fmaf(fmaf(A0, u, c10), u, c00);
            const float g1 = fmaf(fmaf(A1, u, c11), u, c01);
            const float g2 = fmaf(fmaf(A2, v, c12), v, c02);
            const float g3 = fmaf(fmaf(A3, v, c13), v, c03);
            (&ou.x)[j] = fmaf(u, g0, v * g1);
            (&ov.x)[j] = fmaf(u, g2, v * g3);
        }

        out[uoff] = ou;
        out[voff] = ov;
    }
}

extern "C" void kernel_launch(void* const* d_in, const int* in_sizes, int n_in,
                              void* d_out, int out_size, void* d_ws, size_t ws_size,
                              hipStream_t stream) {
    const float* x  = (const float*)d_in[0];
    const float* W1 = (const float*)d_in[1];
    const float* B1 = (const float*)d_in[2];
    const float* W2 = (const float*)d_in[3];
    const float* B2 = (const float*)d_in[4];
    const float* W3 = (const float*)d_in[5];
    const float* B3 = (const float*)d_in[6];
    float* out = (float*)d_out;

    percnn_fused_kernel<<<BLOCKS, THREADS, 0, stream>>>(
        (const float4*)x, (float4*)out, W1, B1, W2, B2, W3, B3);
}

// Round 3
// 11.480 us; speedup vs baseline: 1.2712x; 1.0020x over previous
//
#include <hip/hip_runtime.h>

// x: (8, 2, 512, 512) f32 ; out: (8, 2, 512, 512) f32
// W1,B1,W2,B2,W3: (4,16) f32 ; B3: (4,) f32
//
// grads[k](s) = A[k]*s^2 + B[k]*s + C[k]  with coefficients reduced over c
// (see R0 derivation); k=0,1 at s=u, k=2,3 at s=v.
// out_u = u*g0(u) + v*g1(u) ; out_v = u*g2(v) + v*g3(v)
//
// Single fused kernel. Per-wave coefficient computation lane-parallel over
// the 64-element (4,16) weight arrays + shfl_xor butterfly reduce (overlaps
// with the x loads, which don't depend on it). Main body: 2 rounds per
// thread with ALL FOUR float4 loads hoisted before any compute/store, to
// double in-flight memory ops (latency ramp dominates at this problem size).

#define BATCH  8
#define HW     (512 * 512)
#define HW4    (HW / 4)            // 65536 float4 per plane
#define TOTAL4 (BATCH * HW4)       // 524288 float4 groups per field
#define PER_THREAD 2
#define THREADS 256
#define BLOCKS  (TOTAL4 / (THREADS * PER_THREAD))   // 1024

__global__ __launch_bounds__(THREADS) void percnn_fused_kernel(
        const float4* __restrict__ x,
        float4* __restrict__ out,
        const float* __restrict__ W1,
        const float* __restrict__ B1,
        const float* __restrict__ W2,
        const float* __restrict__ B2,
        const float* __restrict__ W3,
        const float* __restrict__ B3) {
    // ---- main-body addresses & loads FIRST (independent of coefficients) --
    const int tid  = blockIdx.x * THREADS + threadIdx.x;
    const int idx0 = tid;
    const int idx1 = tid + (TOTAL4 / PER_THREAD);

    const int b0 = idx0 >> 16, i0 = idx0 & (HW4 - 1);
    const int b1 = idx1 >> 16, i1 = idx1 & (HW4 - 1);

    const size_t uoff0 = (size_t)(b0 * 2 + 0) * HW4 + i0;
    const size_t voff0 = (size_t)(b0 * 2 + 1) * HW4 + i0;
    const size_t uoff1 = (size_t)(b1 * 2 + 0) * HW4 + i1;
    const size_t voff1 = (size_t)(b1 * 2 + 1) * HW4 + i1;

    const float4 u4a = x[uoff0];
    const float4 v4a = x[voff0];
    const float4 u4b = x[uoff1];
    const float4 v4b = x[voff1];

    // ---- per-wave coefficient computation (lane = k*16 + c) ----
    const int lane = threadIdx.x & 63;
    const float w1 = W1[lane], bb1 = B1[lane];
    const float w2 = W2[lane], bb2 = B2[lane];
    const float w3 = W3[lane];

    float pA = w3 * w1 * w2;
    float pB = w3 * fmaf(w1, bb2, bb1 * w2);
    float pC = w3 * bb1 * bb2;

    #pragma unroll
    for (int off = 8; off >= 1; off >>= 1) {
        pA += __shfl_xor(pA, off);
        pB += __shfl_xor(pB, off);
        pC += __shfl_xor(pC, off);
    }
    const float A0 = __shfl(pA, 0),  A1 = __shfl(pA, 16);
    const float A2 = __shfl(pA, 32), A3 = __shfl(pA, 48);
    const float c10 = __shfl(pB, 0),  c11 = __shfl(pB, 16);
    const float c12 = __shfl(pB, 32), c13 = __shfl(pB, 48);
    const float c00 = __shfl(pC, 0)  + B3[0];
    const float c01 = __shfl(pC, 16) + B3[1];
    const float c02 = __shfl(pC, 32) + B3[2];
    const float c03 = __shfl(pC, 48) + B3[3];

    // ---- compute + store (loads already in flight) ----
    float4 oua, ova, oub, ovb;
    #pragma unroll
    for (int j = 0; j < 4; ++j) {
        {
            const float u = (&u4a.x)[j];
            const float v = (&v4a.x)[j];
            const float g0 = fmaf(fmaf(A0, u, c10), u, c00);
            const float g1 = fmaf(fmaf(A1, u, c11), u, c01);
            const float g2 = fmaf(fmaf(A2, v, c12), v, c02);
            const float g3 = fmaf(fmaf(A3, v, c13), v, c03);
            (&oua.x)[j] = fmaf(u, g0, v * g1);
            (&ova.x)[j] = fmaf(u, g2, v * g3);
        }
        {
            const float u = (&u4b.x)[j];
            const float v = (&v4b.x)[j];
            const float g0 = fmaf(fmaf(A0, u, c10), u, c00);
            const float g1 = fmaf(fmaf(A1, u, c11), u, c01);
            const float g2 = fmaf(fmaf(A2, v, c12), v, c02);
            const float g3 = fmaf(fmaf(A3, v, c13), v, c03);
            (&oub.x)[j] = fmaf(u, g0, v * g1);
            (&ovb.x)[j] = fmaf(u, g2, v * g3);
        }
    }

    out[uoff0] = oua;
    out[voff0] = ova;
    out[uoff1] = oub;
    out[voff1] = ovb;
}

extern "C" void kernel_launch(void* const* d_in, const int* in_sizes, int n_in,
                              void* d_out, int out_size, void* d_ws, size_t ws_size,
                              hipStream_t stream) {
    const float* x  = (const float*)d_in[0];
    const float* W1 = (const float*)d_in[1];
    const float* B1 = (const float*)d_in[2];
    const float* W2 = (const float*)d_in[3];
    const float* B2 = (const float*)d_in[4];
    const float* W3 = (const float*)d_in[5];
    const float* B3 = (const float*)d_in[6];
    float* out = (float*)d_out;

    percnn_fused_kernel<<<BLOCKS, THREADS, 0, stream>>>(
        (const float4*)x, (float4*)out, W1, B1, W2, B2, W3, B3);
}